// Round 24
// baseline (179.261 us; speedup 1.0000x reference)
//
#include <hip/hip_runtime.h>

// VectorQuantizer on MI355X (gfx950)
// z:   [B=128, C=128, H=32, W=32] f32 -> pixel n = b*1024 + hw, channel stride 1024
// emb: [K=256, C=128] f32
// out: [quantized_st 16777216][indices 131072][commit 1][codebook 1] (f32)
//
// Exactness contract (verified absmax=0 rounds 2-23 -- DO NOT CHANGE):
//   d_k = fl( fl(zz - 2*s_k) + ee_k )
//   s_k = sequential fmaf over c ascending; zz = sequential fl(z*z) sum
//   first-occurrence argmin == min over u64 keys (d_bits<<32 | k), d > 0
//
// Round-24 = round-23 (142us steady; pk-FMA, 0 conflicts, VGPR 84) with the
// c4 window loop at #pragma unroll 2: lets the scheduler hoist window i+1's
// 16 independent ds_reads above window i's 64 pk-FMAs (cross-window latency
// overlap). 84 used vs 168 cap leaves ~80 regs for the in-flight window --
// the compiler owns the trade (r18's forced 2x-buffer spilled; this is the
// safe form). Everything else identical.

typedef float f32x4 __attribute__((ext_vector_type(4)));
typedef float f32x2 __attribute__((ext_vector_type(2)));
typedef unsigned long long u64;

#define VQ_C      128
#define VQ_K      256
#define VQ_HW     1024
#define VQ_CHW    (VQ_C * VQ_HW)
#define VQ_NPIX   131072
#define VQ_QELEMS 16777216
#define PXB       64
#define NBLK      (VQ_NPIX / PXB)     // 2048
#define CCH       32                  // channels per chunk
#define NCH       4
#define EROW      144                 // es row stride bytes (8x16B + 16B pad)

// ws layout (floats): [0..255] ee[k]; [256..256+NBLK) per-block loss partials
__global__ void vq_prep(const float* __restrict__ emb, float* __restrict__ ws) {
    int k = threadIdx.x;               // 256 threads = 256 codes
    float s = 0.0f;
#pragma unroll
    for (int c = 0; c < VQ_C; ++c) {
        float e = emb[k * VQ_C + c];
        s = __fadd_rn(s, __fmul_rn(e, e));
    }
    ws[k] = s;
}

__global__ __launch_bounds__(256, 3) void vq_main(const float* __restrict__ z,
                                                  const float* __restrict__ emb,
                                                  const float* __restrict__ ee,
                                                  float* __restrict__ partials,
                                                  float* __restrict__ out) {
    __shared__ float zs[CCH * PXB];        // [c][px], 8 KB
    __shared__ char  es[VQ_K * EROW];      // padded swizzled e tile, 36 KB
    __shared__ float zzs[PXB];
    __shared__ int   iminS[PXB];
    __shared__ float red[4];

    const int tx = threadIdx.x;
    const int cg = tx & 31;                // code group: codes cg*8 .. +8
    const int pg = tx >> 5;                // px group:  px  pg*8 .. +8
    const int n0 = blockIdx.x * PXB;
    const int b  = n0 >> 10;
    const int hw0 = n0 & 1023;             // 64 | 1024 -> no b straddle
    const float* __restrict__ zb = z + (size_t)b * VQ_CHW + hw0;

    // ---- phase A: zz per pixel, exact sequential chain (wave 0; ordered
    //      before consumers by the first in-loop barrier)
    if (tx < PXB) {
        float zz = 0.0f;
#pragma unroll
        for (int c = 0; c < VQ_C; ++c) {
            float v = zb[c * VQ_HW + tx];  // 64-lane coalesced per c
            zz = __fadd_rn(zz, __fmul_rn(v, v));
        }
        zzs[tx] = zz;
    }

    // packed accumulators: acc2[ph][o] = (acc[2ph][o], acc[2ph+1][o])
    f32x2 acc2[4][8];
#pragma unroll
    for (int ph = 0; ph < 4; ++ph)
#pragma unroll
        for (int o = 0; o < 8; ++o) acc2[ph][o] = (f32x2){0.0f, 0.0f};

    const int ci  = tx >> 6;               // z-staging c-lane (wave id)
    const int px  = tx & 63;
    const int swx = ((tx >> 6) ^ (tx >> 3)) & 7;   // write swizzle key (r18-proven)

    // hoisted hot-loop bases (byte pointers, loop-invariant)
    const char* const zbase = (const char*)zs + pg * 32;
    const char* const ebase = es + cg * (8 * EROW);
    const int keysh = (((cg >> 3) ^ cg) & 7) << 4; // read swizzle key (r18-proven)

#pragma unroll 1
    for (int ch = 0; ch < NCH; ++ch) {
        const int c0 = ch * CCH;
        if (ch) __syncthreads();           // protect tiles from overwrite

        // ---- stage z tile [c][px]: coalesced global reads, free LDS writes
#pragma unroll
        for (int i = 0; i < 8; ++i) {
            int c = i * 4 + ci;
            zs[c * PXB + px] = zb[(c0 + c) * VQ_HW + px];
        }
        // ---- stage e tile: thread tx = code row; sequential coalesced loads,
        //      swizzled slot + 144B padded rows -> conflict-free (r19: 0)
        {
            const float* __restrict__ eg = emb + tx * VQ_C + c0;
            char* erow = es + tx * EROW;
#pragma unroll
            for (int c4 = 0; c4 < 8; ++c4) {
                f32x4 v = *(const f32x4*)(eg + c4 * 4);
                *(f32x4*)(erow + ((c4 ^ swx) << 4)) = v;
            }
        }
        __syncthreads();

        // ---- compute: 8 windows of 4 channels; immediate-offset ds reads;
        //      inner product as v_pk_fma_f32 (px pairs); unroll 2 => scheduler
        //      may hoist window i+1's ds_reads over window i's FMA block
#pragma unroll 2
        for (int c4 = 0; c4 < 8; ++c4) {
            const char* eaddr = ebase + ((c4 << 4) ^ keysh);
            f32x4 ef[8];                   // 8 codes x 4 channels
#pragma unroll
            for (int o = 0; o < 8; ++o)
                ef[o] = *(const f32x4*)(eaddr + o * EROW);   // offset:o*144

            f32x4 zf[4][2];                // [j][half]: 8 px of channel c4*4+j
#pragma unroll
            for (int j = 0; j < 4; ++j) {
                zf[j][0] = *(const f32x4*)(zbase + (c4 * 4 + j) * (PXB * 4));
                zf[j][1] = *(const f32x4*)(zbase + (c4 * 4 + j) * (PXB * 4) + 16);
            }
            // c ascending (j outer) => exact per-(px,code) fused-RN chain
#pragma unroll
            for (int j = 0; j < 4; ++j) {
                f32x2 zp[4];               // 4 px-pairs of channel c4*4+j
                zp[0] = (f32x2){zf[j][0][0], zf[j][0][1]};
                zp[1] = (f32x2){zf[j][0][2], zf[j][0][3]};
                zp[2] = (f32x2){zf[j][1][0], zf[j][1][1]};
                zp[3] = (f32x2){zf[j][1][2], zf[j][1][3]};
#pragma unroll
                for (int o = 0; o < 8; ++o) {
                    float ev = ef[o][j];
                    f32x2 ev2 = (f32x2){ev, ev};
#pragma unroll
                    for (int ph = 0; ph < 4; ++ph)
                        acc2[ph][o] = __builtin_elementwise_fma(zp[ph], ev2,
                                                                acc2[ph][o]);
                }
            }
        }
    }

    // ---- d + first-occurrence argmin (u64 keys; d > 0 so bit order = value order)
    float eev[8];
#pragma unroll
    for (int o = 0; o < 8; ++o) eev[o] = ee[cg * 8 + o];

#pragma unroll
    for (int p = 0; p < 8; ++p) {
        float zz = zzs[pg * 8 + p];
        u64 key = ~0ull;
#pragma unroll
        for (int o = 0; o < 8; ++o) {
            float a = acc2[p >> 1][o][p & 1];   // static after unroll
            float d = __fadd_rn(__fsub_rn(zz, __fadd_rn(a, a)), eev[o]);
            union { float f; unsigned u; } du; du.f = d;
            u64 k2 = ((u64)du.u << 32) | (unsigned)(cg * 8 + o);
            if (k2 < key) key = k2;
        }
        // reduce across the 32 code-group threads (one half-wave)
#pragma unroll
        for (int st = 1; st < 32; st <<= 1) {
            u64 o2 = __shfl_xor(key, st, 32);
            if (o2 < key) key = o2;
        }
        if (cg == 0) iminS[pg * 8 + p] = (int)(key & 0xffffffffu);
    }
    __syncthreads();

    // ---- epilogue: thread -> pixel tx&63, channel-block tx>>6 (32 channels)
    const int cb = tx >> 6;
    const int im = iminS[px];
    const float* __restrict__ eq = emb + (size_t)im * VQ_C + cb * 32;
    const float* __restrict__ zp2 = zb + px;
    float* __restrict__ op = out + (size_t)b * VQ_CHW + hw0 + px;
    float lsum = 0.0f;
#pragma unroll
    for (int i = 0; i < 8; ++i) {
        f32x4 e4 = *(const f32x4*)(eq + i * 4);        // divergent L2 gather
#pragma unroll
        for (int j = 0; j < 4; ++j) {
            int c = cb * 32 + i * 4 + j;
            float zv   = zp2[c * VQ_HW];               // L2-hot, exact bits
            float diff = __fsub_rn(e4[j], zv);
            op[c * VQ_HW] = __fadd_rn(zv, diff);       // coalesced per c
            lsum = fmaf(diff, diff, lsum);
        }
    }
    if (tx < PXB) out[VQ_QELEMS + n0 + tx] = (float)iminS[tx];

    // ---- loss partial
#pragma unroll
    for (int off = 32; off > 0; off >>= 1) lsum += __shfl_down(lsum, off, 64);
    if ((tx & 63) == 0) red[tx >> 6] = lsum;
    __syncthreads();
    if (tx == 0)
        partials[blockIdx.x] = (red[0] + red[1]) + (red[2] + red[3]);
}

__global__ void vq_fin(const float* __restrict__ partials, float* __restrict__ out) {
    double acc = 0.0;
    for (int i = 0; i < NBLK; ++i) acc += (double)partials[i];
    float m = (float)(acc * (1.0 / (double)VQ_QELEMS));
    out[VQ_QELEMS + VQ_NPIX + 0] = 0.25f * m;  // commitment
    out[VQ_QELEMS + VQ_NPIX + 1] = m;          // codebook
}

extern "C" void kernel_launch(void* const* d_in, const int* in_sizes, int n_in,
                              void* d_out, int out_size, void* d_ws, size_t ws_size,
                              hipStream_t stream) {
    const float* z   = (const float*)d_in[0];
    const float* emb = (const float*)d_in[1];
    float* out = (float*)d_out;
    float* ws  = (float*)d_ws;            // [0..255]=ee, [256..)=partials

    vq_prep<<<1, 256, 0, stream>>>(emb, ws);
    vq_main<<<NBLK, 256, 0, stream>>>(z, emb, ws, ws + 256, out);
    vq_fin<<<1, 1, 0, stream>>>(ws + 256, out);
}

// Round 25
// 166.901 us; speedup vs baseline: 1.0741x; 1.0741x over previous
//
#include <hip/hip_runtime.h>

// VectorQuantizer on MI355X (gfx950)
// z:   [B=128, C=128, H=32, W=32] f32 -> pixel n = b*1024 + hw, channel stride 1024
// emb: [K=256, C=128] f32
// out: [quantized_st 16777216][indices 131072][commit 1][codebook 1] (f32)
//
// Exactness contract (verified absmax=0 rounds 2-24 -- DO NOT CHANGE):
//   d_k = fl( fl(zz - 2*s_k) + ee_k )
//   s_k = sequential fmaf over c ascending; zz = sequential fl(z*z) sum
//   first-occurrence argmin == min over u64 keys (d_bits<<32 | k), d > 0
//
// Round-25 = round-23 (142us; pk-FMA, 0 conflicts, VGPR 84) + manual 2-deep
// ef pipeline with CORRECT register math: r18 spilled at peak ~170 (zf[4][2]
// =32 regs live through the window); here zf loads move inside the j-loop
// (zfj[2]=8 regs) -> peak ~ acc64+efA32+efB32+zfj8+addr12 = ~156 < 168 cap.
// LOADE(c4+1) issues 8 ds_read_b128 before DOWIN(c4)'s 64 pk-FMAs.

typedef float f32x4 __attribute__((ext_vector_type(4)));
typedef float f32x2 __attribute__((ext_vector_type(2)));
typedef unsigned long long u64;

#define VQ_C      128
#define VQ_K      256
#define VQ_HW     1024
#define VQ_CHW    (VQ_C * VQ_HW)
#define VQ_NPIX   131072
#define VQ_QELEMS 16777216
#define PXB       64
#define NBLK      (VQ_NPIX / PXB)     // 2048
#define CCH       32                  // channels per chunk
#define NCH       4
#define EROW      144                 // es row stride bytes (8x16B + 16B pad)

// ws layout (floats): [0..255] ee[k]; [256..256+NBLK) per-block loss partials
__global__ void vq_prep(const float* __restrict__ emb, float* __restrict__ ws) {
    int k = threadIdx.x;               // 256 threads = 256 codes
    float s = 0.0f;
#pragma unroll
    for (int c = 0; c < VQ_C; ++c) {
        float e = emb[k * VQ_C + c];
        s = __fadd_rn(s, __fmul_rn(e, e));
    }
    ws[k] = s;
}

__global__ __launch_bounds__(256, 3) void vq_main(const float* __restrict__ z,
                                                  const float* __restrict__ emb,
                                                  const float* __restrict__ ee,
                                                  float* __restrict__ partials,
                                                  float* __restrict__ out) {
    __shared__ float zs[CCH * PXB];        // [c][px], 8 KB
    __shared__ char  es[VQ_K * EROW];      // padded swizzled e tile, 36 KB
    __shared__ float zzs[PXB];
    __shared__ int   iminS[PXB];
    __shared__ float red[4];

    const int tx = threadIdx.x;
    const int cg = tx & 31;                // code group: codes cg*8 .. +8
    const int pg = tx >> 5;                // px group:  px  pg*8 .. +8
    const int n0 = blockIdx.x * PXB;
    const int b  = n0 >> 10;
    const int hw0 = n0 & 1023;             // 64 | 1024 -> no b straddle
    const float* __restrict__ zb = z + (size_t)b * VQ_CHW + hw0;

    // ---- phase A: zz per pixel, exact sequential chain (wave 0; ordered
    //      before consumers by the first in-loop barrier)
    if (tx < PXB) {
        float zz = 0.0f;
#pragma unroll
        for (int c = 0; c < VQ_C; ++c) {
            float v = zb[c * VQ_HW + tx];  // 64-lane coalesced per c
            zz = __fadd_rn(zz, __fmul_rn(v, v));
        }
        zzs[tx] = zz;
    }

    // packed accumulators: acc2[ph][o] = (acc[2ph][o], acc[2ph+1][o])
    f32x2 acc2[4][8];
#pragma unroll
    for (int ph = 0; ph < 4; ++ph)
#pragma unroll
        for (int o = 0; o < 8; ++o) acc2[ph][o] = (f32x2){0.0f, 0.0f};

    const int ci  = tx >> 6;               // z-staging c-lane (wave id)
    const int px  = tx & 63;
    const int swx = ((tx >> 6) ^ (tx >> 3)) & 7;   // write swizzle key (r18-proven)

    // hoisted hot-loop bases (byte pointers, loop-invariant)
    const char* const zbase = (const char*)zs + pg * 32;
    const char* const ebase = es + cg * (8 * EROW);
    const int keysh = (((cg >> 3) ^ cg) & 7) << 4; // read swizzle key (r18-proven)

#define LOADE(BUF, C4) do {                                               \
    const char* _ea = ebase + (((C4) << 4) ^ keysh);                      \
    _Pragma("unroll")                                                     \
    for (int _o = 0; _o < 8; ++_o)                                        \
        BUF[_o] = *(const f32x4*)(_ea + _o * EROW);                       \
} while (0)

// zf loads INSIDE the j-loop: only 8 regs of z live at a time (r18 kept 32)
#define DOWIN(BUF, C4) do {                                               \
    _Pragma("unroll")                                                     \
    for (int _j = 0; _j < 4; ++_j) {                                      \
        f32x4 _zf0 = *(const f32x4*)(zbase + ((C4)*4 + _j) * (PXB * 4));  \
        f32x4 _zf1 = *(const f32x4*)(zbase + ((C4)*4 + _j) * (PXB * 4) + 16); \
        f32x2 _zp[4];                                                     \
        _zp[0] = (f32x2){_zf0[0], _zf0[1]};                               \
        _zp[1] = (f32x2){_zf0[2], _zf0[3]};                               \
        _zp[2] = (f32x2){_zf1[0], _zf1[1]};                               \
        _zp[3] = (f32x2){_zf1[2], _zf1[3]};                               \
        _Pragma("unroll")                                                 \
        for (int _o = 0; _o < 8; ++_o) {                                  \
            float _ev = BUF[_o][_j];                                      \
            f32x2 _ev2 = (f32x2){_ev, _ev};                               \
            _Pragma("unroll")                                             \
            for (int _ph = 0; _ph < 4; ++_ph)                             \
                acc2[_ph][_o] = __builtin_elementwise_fma(_zp[_ph], _ev2, \
                                                          acc2[_ph][_o]); \
        }                                                                 \
    }                                                                     \
} while (0)

#pragma unroll 1
    for (int ch = 0; ch < NCH; ++ch) {
        const int c0 = ch * CCH;
        if (ch) __syncthreads();           // protect tiles from overwrite

        // ---- stage z tile [c][px]: coalesced global reads, free LDS writes
#pragma unroll
        for (int i = 0; i < 8; ++i) {
            int c = i * 4 + ci;
            zs[c * PXB + px] = zb[(c0 + c) * VQ_HW + px];
        }
        // ---- stage e tile: thread tx = code row; sequential coalesced loads,
        //      swizzled slot + 144B padded rows -> conflict-free (r19: 0)
        {
            const float* __restrict__ eg = emb + tx * VQ_C + c0;
            char* erow = es + tx * EROW;
#pragma unroll
            for (int c4 = 0; c4 < 8; ++c4) {
                f32x4 v = *(const f32x4*)(eg + c4 * 4);
                *(f32x4*)(erow + ((c4 ^ swx) << 4)) = v;
            }
        }
        __syncthreads();

        // ---- compute: 8 windows, ef 2-deep pipelined (prefetch c4+1 before
        //      FMA of c4); zf streamed per-j inside DOWIN
        {
            f32x4 efA[8], efB[8];
            LOADE(efA, 0);
            LOADE(efB, 1); DOWIN(efA, 0);
            LOADE(efA, 2); DOWIN(efB, 1);
            LOADE(efB, 3); DOWIN(efA, 2);
            LOADE(efA, 4); DOWIN(efB, 3);
            LOADE(efB, 5); DOWIN(efA, 4);
            LOADE(efA, 6); DOWIN(efB, 5);
            LOADE(efB, 7); DOWIN(efA, 6);
            DOWIN(efB, 7);
        }
    }
#undef LOADE
#undef DOWIN

    // ---- d + first-occurrence argmin (u64 keys; d > 0 so bit order = value order)
    float eev[8];
#pragma unroll
    for (int o = 0; o < 8; ++o) eev[o] = ee[cg * 8 + o];

#pragma unroll
    for (int p = 0; p < 8; ++p) {
        float zz = zzs[pg * 8 + p];
        u64 key = ~0ull;
#pragma unroll
        for (int o = 0; o < 8; ++o) {
            float a = acc2[p >> 1][o][p & 1];   // static after unroll
            float d = __fadd_rn(__fsub_rn(zz, __fadd_rn(a, a)), eev[o]);
            union { float f; unsigned u; } du; du.f = d;
            u64 k2 = ((u64)du.u << 32) | (unsigned)(cg * 8 + o);
            if (k2 < key) key = k2;
        }
        // reduce across the 32 code-group threads (one half-wave)
#pragma unroll
        for (int st = 1; st < 32; st <<= 1) {
            u64 o2 = __shfl_xor(key, st, 32);
            if (o2 < key) key = o2;
        }
        if (cg == 0) iminS[pg * 8 + p] = (int)(key & 0xffffffffu);
    }
    __syncthreads();

    // ---- epilogue: thread -> pixel tx&63, channel-block tx>>6 (32 channels)
    const int cb = tx >> 6;
    const int im = iminS[px];
    const float* __restrict__ eq = emb + (size_t)im * VQ_C + cb * 32;
    const float* __restrict__ zp2 = zb + px;
    float* __restrict__ op = out + (size_t)b * VQ_CHW + hw0 + px;
    float lsum = 0.0f;
#pragma unroll
    for (int i = 0; i < 8; ++i) {
        f32x4 e4 = *(const f32x4*)(eq + i * 4);        // divergent L2 gather
#pragma unroll
        for (int j = 0; j < 4; ++j) {
            int c = cb * 32 + i * 4 + j;
            float zv   = zp2[c * VQ_HW];               // L2-hot, exact bits
            float diff = __fsub_rn(e4[j], zv);
            op[c * VQ_HW] = __fadd_rn(zv, diff);       // coalesced per c
            lsum = fmaf(diff, diff, lsum);
        }
    }
    if (tx < PXB) out[VQ_QELEMS + n0 + tx] = (float)iminS[tx];

    // ---- loss partial
#pragma unroll
    for (int off = 32; off > 0; off >>= 1) lsum += __shfl_down(lsum, off, 64);
    if ((tx & 63) == 0) red[tx >> 6] = lsum;
    __syncthreads();
    if (tx == 0)
        partials[blockIdx.x] = (red[0] + red[1]) + (red[2] + red[3]);
}

__global__ void vq_fin(const float* __restrict__ partials, float* __restrict__ out) {
    double acc = 0.0;
    for (int i = 0; i < NBLK; ++i) acc += (double)partials[i];
    float m = (float)(acc * (1.0 / (double)VQ_QELEMS));
    out[VQ_QELEMS + VQ_NPIX + 0] = 0.25f * m;  // commitment
    out[VQ_QELEMS + VQ_NPIX + 1] = m;          // codebook
}

extern "C" void kernel_launch(void* const* d_in, const int* in_sizes, int n_in,
                              void* d_out, int out_size, void* d_ws, size_t ws_size,
                              hipStream_t stream) {
    const float* z   = (const float*)d_in[0];
    const float* emb = (const float*)d_in[1];
    float* out = (float*)d_out;
    float* ws  = (float*)d_ws;            // [0..255]=ee, [256..)=partials

    vq_prep<<<1, 256, 0, stream>>>(emb, ws);
    vq_main<<<NBLK, 256, 0, stream>>>(z, emb, ws, ws + 256, out);
    vq_fin<<<1, 1, 0, stream>>>(ws + 256, out);
}